// Round 1
// baseline (323.117 us; speedup 1.0000x reference)
//
#include <hip/hip_runtime.h>

#define T_DIM 8192
#define E_DIM 1024
#define NB 4
#define NROWS (NB * T_DIM)      // 32768
#define BM 64                   // rows per workgroup in main kernel
#define LDV 68                  // padded LDS row stride (floats) for v tile
#define INV_SQRT8 0.35355339059327373f

typedef __bf16 bf16x8 __attribute__((ext_vector_type(8)));
typedef float f32x4 __attribute__((ext_vector_type(4)));

// ---------------- setup: fold W'=W@w, bf16 tables ----------------
// wph/wpl: [16][1024] bf16 (c-major), hi/lo split of [Wq@w | Wk@w]^T
// WvT:     [64][1024] bf16 (n-major) of Wv
__global__ __launch_bounds__(256) void favor_setup(
    const float* __restrict__ w,     // [64][8]
    const float* __restrict__ Wq,    // [1024][64]
    const float* __restrict__ bq,    // [64]
    const float* __restrict__ Wk,    // [1024][64]
    const float* __restrict__ bk,    // [64]
    const float* __restrict__ Wv,    // [1024][64]
    float* __restrict__ bqw,         // [8]
    float* __restrict__ bkw,         // [8]
    __bf16* __restrict__ wph,
    __bf16* __restrict__ wpl,
    __bf16* __restrict__ WvT)
{
    const int g = blockIdx.x * 256 + threadIdx.x;  // 0..16383
    const int k = g >> 4;
    const int c = g & 15;
    const float* Wsrc = (c < 8) ? Wq : Wk;
    const int cc = c & 7;
    float s = 0.f;
    #pragma unroll 4
    for (int d = 0; d < 64; ++d)
        s += Wsrc[k * 64 + d] * w[d * 8 + cc];
    const __bf16 h = (__bf16)s;
    wph[c * 1024 + k] = h;
    wpl[c * 1024 + k] = (__bf16)(s - (float)h);

    #pragma unroll
    for (int t = 0; t < 4; ++t) {
        const int idx = g * 4 + t;         // covers [64][1024]
        const int n = idx >> 10;
        const int kk = idx & 1023;
        WvT[idx] = (__bf16)Wv[kk * 64 + n];
    }
    if (g < 8) {
        float s1 = 0.f, s2 = 0.f;
        for (int d = 0; d < 64; ++d) {
            s1 += bq[d] * w[d * 8 + g];
            s2 += bk[d] * w[d * 8 + g];
        }
        bqw[g] = s1;
        bkw[g] = s2;
    }
}

// ---------------- main: stream x once; v(MFMA bf16) + p(MFMA split-bf16) ----------------
__global__ __launch_bounds__(256, 2) void favor_main(
    const float* __restrict__ x,      // [NROWS][1024]
    const __bf16* __restrict__ wph,   // [16][1024]
    const __bf16* __restrict__ wpl,   // [16][1024]
    const __bf16* __restrict__ WvT,   // [64][1024]
    const float* __restrict__ bqw,    // [8]
    const float* __restrict__ bkw,    // [8]
    const float* __restrict__ bv,     // [64]
    float* __restrict__ pq_out,       // [NROWS][8]
    float* __restrict__ S)            // [4][16][64]
{
    __shared__ __align__(16) float vb[BM][LDV];  // 17408 B
    __shared__ __align__(16) float kp[BM][16];   // 4096 B

    const int tid  = threadIdx.x;
    const int wg   = blockIdx.x;                                // 0..511
    const int lane = tid & 63;
    const int wv   = __builtin_amdgcn_readfirstlane(tid >> 6);  // wave 0..3
    const int l15  = lane & 15;
    const int quad = lane >> 4;

    // A-operand row for this lane (A[m = lane&15][k = quad*8+j])
    const long grow_a = (long)wg * BM + wv * 16 + l15;
    const float* xa = x + grow_a * E_DIM + quad * 8;

    f32x4 zero = {0.f, 0.f, 0.f, 0.f};
    f32x4 accv[4];
    #pragma unroll
    for (int ct = 0; ct < 4; ++ct) accv[ct] = zero;
    f32x4 accp = zero;

    // B-operand bases: B[k = quad*8+j][n = lane&15], tables stored n-major
    const __bf16* wvt_base = WvT + l15 * E_DIM + quad * 8;
    const __bf16* wph_base = wph + l15 * E_DIM + quad * 8;
    const __bf16* wpl_base = wpl + l15 * E_DIM + quad * 8;

    #pragma unroll 4
    for (int ks = 0; ks < 32; ++ks) {    // 32 k-steps of K=32
        const int k0 = ks * 32;
        const float4 f0 = *(const float4*)(xa + k0);
        const float4 f1 = *(const float4*)(xa + k0 + 4);
        bf16x8 ah, al;
        {
            float f[8] = {f0.x, f0.y, f0.z, f0.w, f1.x, f1.y, f1.z, f1.w};
            #pragma unroll
            for (int i = 0; i < 8; ++i) {
                const __bf16 h = (__bf16)f[i];
                ah[i] = h;
                al[i] = (__bf16)(f[i] - (float)h);
            }
        }
        #pragma unroll
        for (int ct = 0; ct < 4; ++ct) {
            const bf16x8 b = *(const bf16x8*)(wvt_base + ct * 16 * E_DIM + k0);
            accv[ct] = __builtin_amdgcn_mfma_f32_16x16x32_bf16(ah, b, accv[ct], 0, 0, 0);
        }
        {
            const bf16x8 bh = *(const bf16x8*)(wph_base + k0);
            const bf16x8 bl = *(const bf16x8*)(wpl_base + k0);
            accp = __builtin_amdgcn_mfma_f32_16x16x32_bf16(ah, bh, accp, 0, 0, 0);
            accp = __builtin_amdgcn_mfma_f32_16x16x32_bf16(al, bh, accp, 0, 0, 0);
            accp = __builtin_amdgcn_mfma_f32_16x16x32_bf16(ah, bl, accp, 0, 0, 0);
        }
    }

    // ---- p epilogue: accp[r] = P[row = wv*16 + quad*4 + r][c = l15] ----
    if (l15 < 8) {
        const float bq_ = bqw[l15];
        #pragma unroll
        for (int r = 0; r < 4; ++r) {
            const long gr = (long)wg * BM + wv * 16 + quad * 4 + r;
            pq_out[gr * 8 + l15] = accp[r] + bq_;
        }
    } else {
        const float bk_ = bkw[l15 - 8];
        #pragma unroll
        for (int r = 0; r < 4; ++r) {
            const int lr = wv * 16 + quad * 4 + r;
            const float pk_ = accp[r] + bk_;
            kp[lr][l15 - 8] = __cosf(pk_) * INV_SQRT8;
            kp[lr][l15]     = __sinf(pk_) * INV_SQRT8;
        }
    }
    // ---- v epilogue: C/D layout col=lane&15, row=quad*4+reg ----
    #pragma unroll
    for (int ct = 0; ct < 4; ++ct) {
        const float bv_ = bv[ct * 16 + l15];
        #pragma unroll
        for (int r = 0; r < 4; ++r)
            vb[wv * 16 + quad * 4 + r][ct * 16 + l15] = accv[ct][r] + bv_;
    }
    __syncthreads();

    // ---- S partial: S[m][d] += sum_r kp[r][m]*vb[r][d]; then atomicAdd ----
    {
        const int d4 = tid & 15;          // d block of 4
        const int mg = (tid >> 4) & 3;    // m block of 4
        const int rh = tid >> 6;          // row range of 16
        float sa[16];
        #pragma unroll
        for (int i = 0; i < 16; ++i) sa[i] = 0.f;
        #pragma unroll
        for (int rr = 0; rr < 16; ++rr) {
            const int r = rh * 16 + rr;
            const float4 vv  = *(const float4*)&vb[r][d4 * 4];
            const float4 kk4 = *(const float4*)&kp[r][mg * 4];
            const float km[4] = {kk4.x, kk4.y, kk4.z, kk4.w};
            const float vm[4] = {vv.x, vv.y, vv.z, vv.w};
            #pragma unroll
            for (int mi = 0; mi < 4; ++mi)
                #pragma unroll
                for (int di = 0; di < 4; ++di)
                    sa[mi * 4 + di] += km[mi] * vm[di];
        }
        float* Sb = S + (wg >> 7) * 1024;   // batch = wg/128
        #pragma unroll
        for (int mi = 0; mi < 4; ++mi)
            #pragma unroll
            for (int di = 0; di < 4; ++di)
                atomicAdd(&Sb[(mg * 4 + mi) * 64 + d4 * 4 + di], sa[mi * 4 + di]);
    }
}

// ---------------- epilogue: y = [cos(pq),sin(pq)]/sqrt(8) @ S ----------------
__global__ __launch_bounds__(256) void favor_out(
    const float* __restrict__ pq,   // [NROWS][8]
    const float* __restrict__ S,    // [4][16][64]
    float* __restrict__ y)          // [NROWS][64]
{
    const int tid = threadIdx.x;
    const int blk = blockIdx.x;     // 0..511
    const int lane = tid & 63;
    const int w = __builtin_amdgcn_readfirstlane(tid >> 6);  // d-block 0..3
    const long row = (long)blk * 64 + lane;
    const int b = blk >> 7;         // 128 blocks per batch

    const float4 p0 = *(const float4*)(pq + row * 8);
    const float4 p1 = *(const float4*)(pq + row * 8 + 4);
    float qp[16];
    qp[0] = __cosf(p0.x) * INV_SQRT8;  qp[1] = __cosf(p0.y) * INV_SQRT8;
    qp[2] = __cosf(p0.z) * INV_SQRT8;  qp[3] = __cosf(p0.w) * INV_SQRT8;
    qp[4] = __cosf(p1.x) * INV_SQRT8;  qp[5] = __cosf(p1.y) * INV_SQRT8;
    qp[6] = __cosf(p1.z) * INV_SQRT8;  qp[7] = __cosf(p1.w) * INV_SQRT8;
    qp[8] = __sinf(p0.x) * INV_SQRT8;  qp[9] = __sinf(p0.y) * INV_SQRT8;
    qp[10]= __sinf(p0.z) * INV_SQRT8;  qp[11]= __sinf(p0.w) * INV_SQRT8;
    qp[12]= __sinf(p1.x) * INV_SQRT8;  qp[13]= __sinf(p1.y) * INV_SQRT8;
    qp[14]= __sinf(p1.z) * INV_SQRT8;  qp[15]= __sinf(p1.w) * INV_SQRT8;

    const float* Sb = S + b * 1024 + w * 16;   // wave-uniform -> scalar loads
    float a[16];
    #pragma unroll
    for (int i = 0; i < 16; ++i) a[i] = 0.f;
    #pragma unroll
    for (int m = 0; m < 16; ++m) {
        const float4 s0 = *(const float4*)(Sb + m * 64);
        const float4 s1 = *(const float4*)(Sb + m * 64 + 4);
        const float4 s2 = *(const float4*)(Sb + m * 64 + 8);
        const float4 s3 = *(const float4*)(Sb + m * 64 + 12);
        const float qm = qp[m];
        a[0] += qm * s0.x;  a[1] += qm * s0.y;  a[2] += qm * s0.z;  a[3] += qm * s0.w;
        a[4] += qm * s1.x;  a[5] += qm * s1.y;  a[6] += qm * s1.z;  a[7] += qm * s1.w;
        a[8] += qm * s2.x;  a[9] += qm * s2.y;  a[10]+= qm * s2.z;  a[11]+= qm * s2.w;
        a[12]+= qm * s3.x;  a[13]+= qm * s3.y;  a[14]+= qm * s3.z;  a[15]+= qm * s3.w;
    }
    float* yp = y + row * 64 + w * 16;
    *(float4*)(yp)      = make_float4(a[0],  a[1],  a[2],  a[3]);
    *(float4*)(yp + 4)  = make_float4(a[4],  a[5],  a[6],  a[7]);
    *(float4*)(yp + 8)  = make_float4(a[8],  a[9],  a[10], a[11]);
    *(float4*)(yp + 12) = make_float4(a[12], a[13], a[14], a[15]);
}

extern "C" void kernel_launch(void* const* d_in, const int* in_sizes, int n_in,
                              void* d_out, int out_size, void* d_ws, size_t ws_size,
                              hipStream_t stream) {
    const float* x  = (const float*)d_in[0];
    const float* w  = (const float*)d_in[1];
    const float* Wq = (const float*)d_in[2];
    const float* bq = (const float*)d_in[3];
    const float* Wk = (const float*)d_in[4];
    const float* bk = (const float*)d_in[5];
    const float* Wv = (const float*)d_in[6];
    const float* bv = (const float*)d_in[7];
    float* y = (float*)d_out;

    char* ws = (char*)d_ws;
    float*  S   = (float*)(ws);            // 16384 B  [4][16][64]
    float*  bqw = (float*)(ws + 16384);    // 32 B
    float*  bkw = (float*)(ws + 16448);    // 32 B
    __bf16* wph = (__bf16*)(ws + 32768);   // 32768 B  [16][1024]
    __bf16* wpl = (__bf16*)(ws + 65536);   // 32768 B  [16][1024]
    __bf16* WvT = (__bf16*)(ws + 98304);   // 131072 B [64][1024]
    float*  pq  = (float*)(ws + 262144);   // 1 MB     [32768][8]

    hipMemsetAsync(S, 0, 4 * 16 * 64 * sizeof(float), stream);
    favor_setup<<<64, 256, 0, stream>>>(w, Wq, bq, Wk, bk, Wv, bqw, bkw, wph, wpl, WvT);
    favor_main<<<512, 256, 0, stream>>>(x, wph, wpl, WvT, bqw, bkw, bv, pq, S);
    favor_out<<<512, 256, 0, stream>>>(pq, S, y);
}

// Round 2
// 304.589 us; speedup vs baseline: 1.0608x; 1.0608x over previous
//
#include <hip/hip_runtime.h>

#define T_DIM 8192
#define E_DIM 1024
#define NB 4
#define NROWS (NB * T_DIM)      // 32768
#define BM 32                   // rows per workgroup in main kernel
#define LDV 68                  // padded LDS row stride (floats) for v tile
#define INV_SQRT8 0.35355339059327373f

typedef __bf16 bf16x8 __attribute__((ext_vector_type(8)));
typedef float f32x4 __attribute__((ext_vector_type(4)));

// ---------------- setup: fold W'=W@w, bf16 tables ----------------
__global__ __launch_bounds__(256) void favor_setup(
    const float* __restrict__ w,     // [64][8]
    const float* __restrict__ Wq,    // [1024][64]
    const float* __restrict__ bq,    // [64]
    const float* __restrict__ Wk,    // [1024][64]
    const float* __restrict__ bk,    // [64]
    const float* __restrict__ Wv,    // [1024][64]
    float* __restrict__ bqw,         // [8]
    float* __restrict__ bkw,         // [8]
    __bf16* __restrict__ wph,
    __bf16* __restrict__ wpl,
    __bf16* __restrict__ WvT)
{
    const int g = blockIdx.x * 256 + threadIdx.x;  // 0..16383
    const int k = g >> 4;
    const int c = g & 15;
    const float* Wsrc = (c < 8) ? Wq : Wk;
    const int cc = c & 7;
    float s = 0.f;
    #pragma unroll 8
    for (int d = 0; d < 64; ++d)
        s += Wsrc[k * 64 + d] * w[d * 8 + cc];
    const __bf16 h = (__bf16)s;
    wph[c * 1024 + k] = h;
    wpl[c * 1024 + k] = (__bf16)(s - (float)h);

    #pragma unroll
    for (int t = 0; t < 4; ++t) {
        const int idx = g * 4 + t;         // covers [64][1024]
        const int n = idx >> 10;
        const int kk = idx & 1023;
        WvT[idx] = (__bf16)Wv[kk * 64 + n];
    }
    if (g < 16) {
        const int col = g & 7;
        const float* bb = (g < 8) ? bq : bk;
        float s1 = 0.f;
        #pragma unroll 8
        for (int d = 0; d < 64; ++d)
            s1 += bb[d] * w[d * 8 + col];
        if (g < 8) bqw[col] = s1; else bkw[col] = s1;
    }
}

// ---------------- main: stream x once; v(MFMA bf16) + p(MFMA split-bf16) ----------------
// grid 1024 x 256. Block covers 32 rows. Waves: rh = wv&1 (row half),
// kh = wv>>1 (k half). Each wave: 16 k-steps of K=32 over its half of K.
__global__ __launch_bounds__(256, 4) void favor_main(
    const float* __restrict__ x,      // [NROWS][1024]
    const __bf16* __restrict__ wph,   // [16][1024]
    const __bf16* __restrict__ wpl,   // [16][1024]
    const __bf16* __restrict__ WvT,   // [64][1024]
    const float* __restrict__ bqw,    // [8]
    const float* __restrict__ bkw,    // [8]
    const float* __restrict__ bv,     // [64]
    float* __restrict__ pq_out,       // [NROWS][8]
    float* __restrict__ S)            // [4][16][64]
{
    __shared__ __align__(16) float vb[BM][LDV];        // 8704 B
    __shared__ __align__(16) float kp[BM][16];         // 2048 B
    __shared__ __align__(16) float cmb[2][64][21];     // 10752 B (pad 21: conflict-free)
    __shared__ __align__(16) float sred[3][64][17];    // 13056 B (pad 17)

    const int tid  = threadIdx.x;
    const int wg   = blockIdx.x;                                // 0..1023
    const int lane = tid & 63;
    const int wv   = __builtin_amdgcn_readfirstlane(tid >> 6);  // wave 0..3
    const int rh   = wv & 1;    // row half (16 rows)
    const int kh   = wv >> 1;   // k half   (512 cols)
    const int l15  = lane & 15;
    const int quad = lane >> 4;

    // A-operand row for this lane (A[m = lane&15][k = quad*8+j])
    const long grow_a = (long)wg * BM + rh * 16 + l15;
    const float* xa = x + grow_a * E_DIM + quad * 8 + kh * 512;

    f32x4 zero = {0.f, 0.f, 0.f, 0.f};
    f32x4 accv[4];
    #pragma unroll
    for (int ct = 0; ct < 4; ++ct) accv[ct] = zero;
    f32x4 accp = zero;

    // B-operand bases: B[k = quad*8+j][n = lane&15], tables stored n-major
    const __bf16* wvt_b = WvT + l15 * E_DIM + quad * 8 + kh * 512;
    const __bf16* wph_b = wph + l15 * E_DIM + quad * 8 + kh * 512;
    const __bf16* wpl_b = wpl + l15 * E_DIM + quad * 8 + kh * 512;

    float4 fa[3][2];   // depth-3 A prefetch (HBM)
    bf16x8 bb[2][6];   // depth-2 B prefetch (L2)

#define A_LOAD(st) { const int _k0 = (st) * 32;                       \
        fa[(st) % 3][0] = *(const float4*)(xa + _k0);                 \
        fa[(st) % 3][1] = *(const float4*)(xa + _k0 + 4); }
#define B_LOAD(st) { const int _k0 = (st) * 32;                       \
        bb[(st) & 1][0] = *(const bf16x8*)(wvt_b + 0 * 16 * E_DIM + _k0); \
        bb[(st) & 1][1] = *(const bf16x8*)(wvt_b + 1 * 16 * E_DIM + _k0); \
        bb[(st) & 1][2] = *(const bf16x8*)(wvt_b + 2 * 16 * E_DIM + _k0); \
        bb[(st) & 1][3] = *(const bf16x8*)(wvt_b + 3 * 16 * E_DIM + _k0); \
        bb[(st) & 1][4] = *(const bf16x8*)(wph_b + _k0);              \
        bb[(st) & 1][5] = *(const bf16x8*)(wpl_b + _k0); }

    A_LOAD(0)
    A_LOAD(1)
    B_LOAD(0)

    #pragma unroll
    for (int ks = 0; ks < 16; ++ks) {
        if (ks + 2 < 16) A_LOAD(ks + 2)
        if (ks + 1 < 16) B_LOAD(ks + 1)
        const float4 f0 = fa[ks % 3][0];
        const float4 f1 = fa[ks % 3][1];
        bf16x8 ah, al;
        {
            const float f[8] = {f0.x, f0.y, f0.z, f0.w, f1.x, f1.y, f1.z, f1.w};
            #pragma unroll
            for (int i = 0; i < 8; ++i) {
                const __bf16 h = (__bf16)f[i];
                ah[i] = h;
                al[i] = (__bf16)(f[i] - (float)h);
            }
        }
        #pragma unroll
        for (int ct = 0; ct < 4; ++ct)
            accv[ct] = __builtin_amdgcn_mfma_f32_16x16x32_bf16(ah, bb[ks & 1][ct], accv[ct], 0, 0, 0);
        accp = __builtin_amdgcn_mfma_f32_16x16x32_bf16(ah, bb[ks & 1][4], accp, 0, 0, 0);
        accp = __builtin_amdgcn_mfma_f32_16x16x32_bf16(al, bb[ks & 1][4], accp, 0, 0, 0);
        accp = __builtin_amdgcn_mfma_f32_16x16x32_bf16(ah, bb[ks & 1][5], accp, 0, 0, 0);
    }
#undef A_LOAD
#undef B_LOAD

    // ---- combine K-halves through LDS ----
    if (kh == 1) {
        #pragma unroll
        for (int ct = 0; ct < 4; ++ct)
            #pragma unroll
            for (int r = 0; r < 4; ++r)
                cmb[rh][lane][ct * 4 + r] = accv[ct][r];
        #pragma unroll
        for (int r = 0; r < 4; ++r)
            cmb[rh][lane][16 + r] = accp[r];
    }
    __syncthreads();
    if (kh == 0) {
        #pragma unroll
        for (int ct = 0; ct < 4; ++ct)
            #pragma unroll
            for (int r = 0; r < 4; ++r)
                accv[ct][r] += cmb[rh][lane][ct * 4 + r];
        #pragma unroll
        for (int r = 0; r < 4; ++r)
            accp[r] += cmb[rh][lane][16 + r];

        // ---- p epilogue: accp[r] = P[row = rh*16 + quad*4 + r][c = l15] ----
        if (l15 < 8) {
            const float bq_ = bqw[l15];
            #pragma unroll
            for (int r = 0; r < 4; ++r) {
                const long gr = (long)wg * BM + rh * 16 + quad * 4 + r;
                pq_out[gr * 8 + l15] = accp[r] + bq_;
            }
        } else {
            const float bk_ = bkw[l15 - 8];
            #pragma unroll
            for (int r = 0; r < 4; ++r) {
                const int lr = rh * 16 + quad * 4 + r;
                const float pk_ = accp[r] + bk_;
                kp[lr][l15 - 8] = __cosf(pk_) * INV_SQRT8;
                kp[lr][l15]     = __sinf(pk_) * INV_SQRT8;
            }
        }
        // ---- v epilogue: C/D layout col=lane&15, row=quad*4+reg ----
        #pragma unroll
        for (int ct = 0; ct < 4; ++ct) {
            const float bv_ = bv[ct * 16 + l15];
            #pragma unroll
            for (int r = 0; r < 4; ++r)
                vb[rh * 16 + quad * 4 + r][ct * 16 + l15] = accv[ct][r] + bv_;
        }
    }
    __syncthreads();

    // ---- S partial: S[m][d] += sum_r kp[r][m]*vb[r][d] over 32 rows ----
    {
        const int d4 = tid & 15;          // d block of 4
        const int mg = (tid >> 4) & 3;    // m block of 4
        const int rq = tid >> 6;          // row quarter (8 rows)
        float sa[16];
        #pragma unroll
        for (int i = 0; i < 16; ++i) sa[i] = 0.f;
        #pragma unroll
        for (int rr = 0; rr < 8; ++rr) {
            const int r = rq * 8 + rr;
            const float4 vv  = *(const float4*)&vb[r][d4 * 4];
            const float4 kk4 = *(const float4*)&kp[r][mg * 4];
            const float km[4] = {kk4.x, kk4.y, kk4.z, kk4.w};
            const float vm[4] = {vv.x, vv.y, vv.z, vv.w};
            #pragma unroll
            for (int mi = 0; mi < 4; ++mi)
                #pragma unroll
                for (int di = 0; di < 4; ++di)
                    sa[mi * 4 + di] += km[mi] * vm[di];
        }
        if (rq > 0) {
            #pragma unroll
            for (int i = 0; i < 16; ++i)
                sred[rq - 1][tid & 63][i] = sa[i];
        }
        __syncthreads();
        if (rq == 0) {
            #pragma unroll
            for (int j = 0; j < 3; ++j)
                #pragma unroll
                for (int i = 0; i < 16; ++i)
                    sa[i] += sred[j][tid][i];
            float* Sb = S + (wg >> 8) * 1024;   // 256 blocks per batch
            #pragma unroll
            for (int mi = 0; mi < 4; ++mi)
                #pragma unroll
                for (int di = 0; di < 4; ++di)
                    atomicAdd(&Sb[(mg * 4 + mi) * 64 + d4 * 4 + di], sa[mi * 4 + di]);
        }
    }
}

// ---------------- epilogue: y = [cos(pq),sin(pq)]/sqrt(8) @ S ----------------
__global__ __launch_bounds__(256) void favor_out(
    const float* __restrict__ pq,   // [NROWS][8]
    const float* __restrict__ S,    // [4][16][64]
    float* __restrict__ y)          // [NROWS][64]
{
    const int tid = threadIdx.x;
    const int blk = blockIdx.x;     // 0..511
    const int lane = tid & 63;
    const int w = __builtin_amdgcn_readfirstlane(tid >> 6);  // d-block 0..3
    const long row = (long)blk * 64 + lane;
    const int b = blk >> 7;         // 128 blocks per batch

    const float4 p0 = *(const float4*)(pq + row * 8);
    const float4 p1 = *(const float4*)(pq + row * 8 + 4);
    float qp[16];
    qp[0] = __cosf(p0.x) * INV_SQRT8;  qp[1] = __cosf(p0.y) * INV_SQRT8;
    qp[2] = __cosf(p0.z) * INV_SQRT8;  qp[3] = __cosf(p0.w) * INV_SQRT8;
    qp[4] = __cosf(p1.x) * INV_SQRT8;  qp[5] = __cosf(p1.y) * INV_SQRT8;
    qp[6] = __cosf(p1.z) * INV_SQRT8;  qp[7] = __cosf(p1.w) * INV_SQRT8;
    qp[8] = __sinf(p0.x) * INV_SQRT8;  qp[9] = __sinf(p0.y) * INV_SQRT8;
    qp[10]= __sinf(p0.z) * INV_SQRT8;  qp[11]= __sinf(p0.w) * INV_SQRT8;
    qp[12]= __sinf(p1.x) * INV_SQRT8;  qp[13]= __sinf(p1.y) * INV_SQRT8;
    qp[14]= __sinf(p1.z) * INV_SQRT8;  qp[15]= __sinf(p1.w) * INV_SQRT8;

    const float* Sb = S + b * 1024 + w * 16;   // wave-uniform -> scalar loads
    float a[16];
    #pragma unroll
    for (int i = 0; i < 16; ++i) a[i] = 0.f;
    #pragma unroll
    for (int m = 0; m < 16; ++m) {
        const float4 s0 = *(const float4*)(Sb + m * 64);
        const float4 s1 = *(const float4*)(Sb + m * 64 + 4);
        const float4 s2 = *(const float4*)(Sb + m * 64 + 8);
        const float4 s3 = *(const float4*)(Sb + m * 64 + 12);
        const float qm = qp[m];
        a[0] += qm * s0.x;  a[1] += qm * s0.y;  a[2] += qm * s0.z;  a[3] += qm * s0.w;
        a[4] += qm * s1.x;  a[5] += qm * s1.y;  a[6] += qm * s1.z;  a[7] += qm * s1.w;
        a[8] += qm * s2.x;  a[9] += qm * s2.y;  a[10]+= qm * s2.z;  a[11]+= qm * s2.w;
        a[12]+= qm * s3.x;  a[13]+= qm * s3.y;  a[14]+= qm * s3.z;  a[15]+= qm * s3.w;
    }
    float* yp = y + row * 64 + w * 16;
    *(float4*)(yp)      = make_float4(a[0],  a[1],  a[2],  a[3]);
    *(float4*)(yp + 4)  = make_float4(a[4],  a[5],  a[6],  a[7]);
    *(float4*)(yp + 8)  = make_float4(a[8],  a[9],  a[10], a[11]);
    *(float4*)(yp + 12) = make_float4(a[12], a[13], a[14], a[15]);
}

extern "C" void kernel_launch(void* const* d_in, const int* in_sizes, int n_in,
                              void* d_out, int out_size, void* d_ws, size_t ws_size,
                              hipStream_t stream) {
    const float* x  = (const float*)d_in[0];
    const float* w  = (const float*)d_in[1];
    const float* Wq = (const float*)d_in[2];
    const float* bq = (const float*)d_in[3];
    const float* Wk = (const float*)d_in[4];
    const float* bk = (const float*)d_in[5];
    const float* Wv = (const float*)d_in[6];
    const float* bv = (const float*)d_in[7];
    float* y = (float*)d_out;

    char* ws = (char*)d_ws;
    float*  S   = (float*)(ws);            // 16384 B  [4][16][64]
    float*  bqw = (float*)(ws + 16384);    // 32 B
    float*  bkw = (float*)(ws + 16448);    // 32 B
    __bf16* wph = (__bf16*)(ws + 32768);   // 32768 B  [16][1024]
    __bf16* wpl = (__bf16*)(ws + 65536);   // 32768 B  [16][1024]
    __bf16* WvT = (__bf16*)(ws + 98304);   // 131072 B [64][1024]
    float*  pq  = (float*)(ws + 262144);   // 1 MB     [32768][8]

    hipMemsetAsync(S, 0, 4 * 16 * 64 * sizeof(float), stream);
    favor_setup<<<64, 256, 0, stream>>>(w, Wq, bq, Wk, bk, Wv, bqw, bkw, wph, wpl, WvT);
    favor_main<<<1024, 256, 0, stream>>>(x, wph, wpl, WvT, bqw, bkw, bv, pq, S);
    favor_out<<<512, 256, 0, stream>>>(pq, S, y);
}

// Round 3
// 276.118 us; speedup vs baseline: 1.1702x; 1.1031x over previous
//
#include <hip/hip_runtime.h>

#define E_DIM 1024
#define NROWS 32768
#define LDA 132                 // LDS tile row stride (floats): 4-float pad
#define INV_SQRT8 0.35355339059327373f

typedef __bf16 bf16x8 __attribute__((ext_vector_type(8)));
typedef float f32x4 __attribute__((ext_vector_type(4)));

// ---------------- setup: fold W'=W@w, emit MFMA-fragment-swizzled bf16 tables ----------------
// WpHS/WpLS: [32 step][64 lane][8 j]  (hi/lo split of [Wq@w | Wk@w], B-frag order)
// WvS:       [4 ct][32 step][64 lane][8 j] of Wv (B-frag order)
__global__ __launch_bounds__(256) void favor_setup(
    const float* __restrict__ w,     // [64][8]
    const float* __restrict__ Wq,    // [1024][64]
    const float* __restrict__ bq,    // [64]
    const float* __restrict__ Wk,    // [1024][64]
    const float* __restrict__ bk,    // [64]
    const float* __restrict__ Wv,    // [1024][64]
    float* __restrict__ bqw,         // [8]
    float* __restrict__ bkw,         // [8]
    __bf16* __restrict__ WpHS,
    __bf16* __restrict__ WpLS,
    __bf16* __restrict__ WvS)
{
    const int g = blockIdx.x * 256 + threadIdx.x;  // 0..16383
    // ---- p-tables: fold (k, c) ----
    {
        const int k = g >> 4;
        const int c = g & 15;
        const float* Wsrc = (c < 8) ? Wq : Wk;
        const int cc = c & 7;
        float s = 0.f;
        #pragma unroll 8
        for (int d = 0; d < 64; ++d)
            s += Wsrc[k * 64 + d] * w[d * 8 + cc];
        const __bf16 h = (__bf16)s;
        const int step = k >> 5, quad = (k >> 3) & 3, j = k & 7;
        const int lane = quad * 16 + c;
        const int idx = (step * 64 + lane) * 8 + j;
        WpHS[idx] = h;
        WpLS[idx] = (__bf16)(s - (float)h);
    }
    // ---- WvS swizzle: 4 elements per thread ----
    #pragma unroll
    for (int t = 0; t < 4; ++t) {
        const int idx = g * 4 + t;        // [0, 65536)
        const int n = idx >> 10;          // 0..63
        const int k = idx & 1023;
        const int ct = n >> 4, l15 = n & 15;
        const int step = k >> 5, quad = (k >> 3) & 3, j = k & 7;
        const int lane = quad * 16 + l15;
        WvS[(((ct * 32 + step) * 64) + lane) * 8 + j] = (__bf16)Wv[k * 64 + n];
    }
    if (g < 16) {
        const int col = g & 7;
        const float* bb = (g < 8) ? bq : bk;
        float s1 = 0.f;
        #pragma unroll 8
        for (int d = 0; d < 64; ++d)
            s1 += bb[d] * w[d * 8 + col];
        if (g < 8) bqw[col] = s1; else bkw[col] = s1;
    }
}

// ---------------- main ----------------
// grid 1024 x 256. Block = 32 rows, full K=1024. Wave wv = k-quarter.
// 8 stages of 128 cols: stage tile in LDS (coalesced), wave wv computes
// k-step gs = s*4+wv from LDS fragments + swizzled B tables (contiguous 1KB loads).
__global__ __launch_bounds__(256, 4) void favor_main(
    const float* __restrict__ x,      // [NROWS][1024]
    const __bf16* __restrict__ WvS,   // [4][32][64][8]
    const __bf16* __restrict__ WpHS,  // [32][64][8]
    const __bf16* __restrict__ WpLS,  // [32][64][8]
    const float* __restrict__ bqw,    // [8]
    const float* __restrict__ bkw,    // [8]
    const float* __restrict__ bv,     // [64]
    float* __restrict__ pq_out,       // [NROWS][8]
    float* __restrict__ Sbkt)         // [32][4][16][64]
{
    __shared__ __align__(16) float smem[2 * 32 * LDA];   // 33792 B
    float* tile0 = smem;
    float* tile1 = smem + 32 * LDA;
    // overlays (float offsets), all dead/live phases separated by barriers:
    float* bufA = smem;          // [64][44] combine payload (wv1)
    float* bufB = smem + 2816;   // (wv3)
    float* bufC = smem + 5632;   // (wv2 round 2)
    float* vb   = smem;          // [32][68]  (over bufA after it dies)
    float* kp   = smem + 2176;   // [32][16]
    float* sred = smem + 2688;   // [3][64][20]

    const int tid  = threadIdx.x;
    const int wg   = blockIdx.x;                                // 0..1023
    const int lane = tid & 63;
    const int wv   = __builtin_amdgcn_readfirstlane(tid >> 6);  // k-quarter 0..3
    const int l15  = lane & 15;
    const int quad = lane >> 4;

    // staging: thread t covers rows {t>>5 + 8i}, cols (t&31)*4..+4 of each 128-col stage
    const int srow = tid >> 5;
    const int scol = (tid & 31) * 4;
    const float* xg = x + (long)(wg * 32 + srow) * E_DIM + scol;

    // A-fragment LDS offsets: rows rh*16+l15, cols wv*32 + quad*8
    const int fra0 = l15 * LDA + wv * 32 + quad * 8;
    const int fra1 = fra0 + 16 * LDA;

    f32x4 zero = {0.f, 0.f, 0.f, 0.f};
    f32x4 accv[4][2];
    #pragma unroll
    for (int ct = 0; ct < 4; ++ct) { accv[ct][0] = zero; accv[ct][1] = zero; }
    f32x4 accp[2] = {zero, zero};

    float4 st[4];
    #pragma unroll
    for (int i = 0; i < 4; ++i) st[i] = *(const float4*)(xg + i * 8192);

    for (int s = 0; s < 8; ++s) {
        float* wb = (s & 1) ? tile1 : tile0;
        #pragma unroll
        for (int i = 0; i < 4; ++i)
            *(float4*)(wb + (srow + i * 8) * LDA + scol) = st[i];
        if (s < 7) {
            #pragma unroll
            for (int i = 0; i < 4; ++i)
                st[i] = *(const float4*)(xg + (s + 1) * 128 + i * 8192);
        }
        __syncthreads();

        // A fragments (both row halves) + split-bf16 conversion
        bf16x8 ah0, al0, ah1, al1;
        {
            const float4 a0 = *(const float4*)(wb + fra0);
            const float4 a1 = *(const float4*)(wb + fra0 + 4);
            const float f[8] = {a0.x, a0.y, a0.z, a0.w, a1.x, a1.y, a1.z, a1.w};
            #pragma unroll
            for (int i = 0; i < 8; ++i) {
                const __bf16 h = (__bf16)f[i];
                ah0[i] = h; al0[i] = (__bf16)(f[i] - (float)h);
            }
        }
        {
            const float4 a0 = *(const float4*)(wb + fra1);
            const float4 a1 = *(const float4*)(wb + fra1 + 4);
            const float f[8] = {a0.x, a0.y, a0.z, a0.w, a1.x, a1.y, a1.z, a1.w};
            #pragma unroll
            for (int i = 0; i < 8; ++i) {
                const __bf16 h = (__bf16)f[i];
                ah1[i] = h; al1[i] = (__bf16)(f[i] - (float)h);
            }
        }
        const int gs = s * 4 + wv;
        const __bf16* bp = WvS + (long)gs * 512 + lane * 8;
        #pragma unroll
        for (int ct = 0; ct < 4; ++ct) {
            const bf16x8 b = *(const bf16x8*)(bp + ct * 16384);
            accv[ct][0] = __builtin_amdgcn_mfma_f32_16x16x32_bf16(ah0, b, accv[ct][0], 0, 0, 0);
            accv[ct][1] = __builtin_amdgcn_mfma_f32_16x16x32_bf16(ah1, b, accv[ct][1], 0, 0, 0);
        }
        {
            const bf16x8 bh = *(const bf16x8*)(WpHS + (long)gs * 512 + lane * 8);
            const bf16x8 bl = *(const bf16x8*)(WpLS + (long)gs * 512 + lane * 8);
            accp[0] = __builtin_amdgcn_mfma_f32_16x16x32_bf16(ah0, bh, accp[0], 0, 0, 0);
            accp[0] = __builtin_amdgcn_mfma_f32_16x16x32_bf16(al0, bh, accp[0], 0, 0, 0);
            accp[0] = __builtin_amdgcn_mfma_f32_16x16x32_bf16(ah0, bl, accp[0], 0, 0, 0);
            accp[1] = __builtin_amdgcn_mfma_f32_16x16x32_bf16(ah1, bh, accp[1], 0, 0, 0);
            accp[1] = __builtin_amdgcn_mfma_f32_16x16x32_bf16(al1, bh, accp[1], 0, 0, 0);
            accp[1] = __builtin_amdgcn_mfma_f32_16x16x32_bf16(ah1, bl, accp[1], 0, 0, 0);
        }
    }
    __syncthreads();   // all tile reads done; smem reusable

    // ---- combine k-quarters: tree through LDS ----
    if (wv == 1 || wv == 3) {
        float* dst = ((wv == 1) ? bufA : bufB) + lane * 44;
        #pragma unroll
        for (int ct = 0; ct < 4; ++ct) {
            *(f32x4*)(dst + (ct * 2 + 0) * 4) = accv[ct][0];
            *(f32x4*)(dst + (ct * 2 + 1) * 4) = accv[ct][1];
        }
        *(f32x4*)(dst + 32) = accp[0];
        *(f32x4*)(dst + 36) = accp[1];
    }
    __syncthreads();
    if (wv == 0 || wv == 2) {
        const float* src = ((wv == 0) ? bufA : bufB) + lane * 44;
        #pragma unroll
        for (int ct = 0; ct < 4; ++ct) {
            accv[ct][0] += *(const f32x4*)(src + (ct * 2 + 0) * 4);
            accv[ct][1] += *(const f32x4*)(src + (ct * 2 + 1) * 4);
        }
        accp[0] += *(const f32x4*)(src + 32);
        accp[1] += *(const f32x4*)(src + 36);
    }
    if (wv == 2) {
        float* dst = bufC + lane * 44;
        #pragma unroll
        for (int ct = 0; ct < 4; ++ct) {
            *(f32x4*)(dst + (ct * 2 + 0) * 4) = accv[ct][0];
            *(f32x4*)(dst + (ct * 2 + 1) * 4) = accv[ct][1];
        }
        *(f32x4*)(dst + 32) = accp[0];
        *(f32x4*)(dst + 36) = accp[1];
    }
    __syncthreads();
    if (wv == 0) {
        const float* src = bufC + lane * 44;
        #pragma unroll
        for (int ct = 0; ct < 4; ++ct) {
            accv[ct][0] += *(const f32x4*)(src + (ct * 2 + 0) * 4);
            accv[ct][1] += *(const f32x4*)(src + (ct * 2 + 1) * 4);
        }
        accp[0] += *(const f32x4*)(src + 32);
        accp[1] += *(const f32x4*)(src + 36);

        // ---- p epilogue: accp[rh][r] = P[row = rh*16 + quad*4 + r][c = l15] ----
        if (l15 < 8) {
            const float bq_ = bqw[l15];
            #pragma unroll
            for (int rh = 0; rh < 2; ++rh)
                #pragma unroll
                for (int r = 0; r < 4; ++r) {
                    const long gr = (long)wg * 32 + rh * 16 + quad * 4 + r;
                    pq_out[gr * 8 + l15] = accp[rh][r] + bq_;
                }
        } else {
            const float bk_ = bkw[l15 - 8];
            #pragma unroll
            for (int rh = 0; rh < 2; ++rh)
                #pragma unroll
                for (int r = 0; r < 4; ++r) {
                    const int lr = rh * 16 + quad * 4 + r;
                    const float pk_ = accp[rh][r] + bk_;
                    kp[lr * 16 + (l15 - 8)] = __cosf(pk_) * INV_SQRT8;
                    kp[lr * 16 + l15]       = __sinf(pk_) * INV_SQRT8;
                }
        }
        // ---- v epilogue ----
        #pragma unroll
        for (int ct = 0; ct < 4; ++ct) {
            const float bv_ = bv[ct * 16 + l15];
            #pragma unroll
            for (int rh = 0; rh < 2; ++rh)
                #pragma unroll
                for (int r = 0; r < 4; ++r)
                    vb[(rh * 16 + quad * 4 + r) * 68 + ct * 16 + l15] = accv[ct][rh][r] + bv_;
        }
    }
    __syncthreads();

    // ---- S partial: S[m][d] += sum_r kp[r][m]*vb[r][d] over 32 rows ----
    {
        const int d4 = l15;          // d block of 4
        const int mg = quad;         // m block of 4
        const int rq = wv;           // row quarter (8 rows)
        float sa[16];
        #pragma unroll
        for (int i = 0; i < 16; ++i) sa[i] = 0.f;
        #pragma unroll
        for (int rr = 0; rr < 8; ++rr) {
            const int r = rq * 8 + rr;
            const float4 vv  = *(const float4*)(vb + r * 68 + d4 * 4);
            const float4 kk4 = *(const float4*)(kp + r * 16 + mg * 4);
            const float km[4] = {kk4.x, kk4.y, kk4.z, kk4.w};
            const float vm[4] = {vv.x, vv.y, vv.z, vv.w};
            #pragma unroll
            for (int mi = 0; mi < 4; ++mi)
                #pragma unroll
                for (int di = 0; di < 4; ++di)
                    sa[mi * 4 + di] += km[mi] * vm[di];
        }
        if (rq > 0) {
            float* dst = sred + (rq - 1) * 1280 + lane * 20;
            #pragma unroll
            for (int i = 0; i < 4; ++i)
                *(float4*)(dst + i * 4) = make_float4(sa[i*4], sa[i*4+1], sa[i*4+2], sa[i*4+3]);
        }
        __syncthreads();
        if (rq == 0) {
            #pragma unroll
            for (int j = 0; j < 3; ++j) {
                const float* src = sred + j * 1280 + lane * 20;
                #pragma unroll
                for (int i = 0; i < 16; ++i) sa[i] += src[i];
            }
            float* Sb = Sbkt + ((long)(wg & 31) * 4 + (wg >> 8)) * 1024;
            #pragma unroll
            for (int mi = 0; mi < 4; ++mi)
                #pragma unroll
                for (int di = 0; di < 4; ++di)
                    atomicAdd(&Sb[(mg * 4 + mi) * 64 + d4 * 4 + di], sa[mi * 4 + di]);
        }
    }
}

// ---------------- reduce buckets -> S ----------------
__global__ __launch_bounds__(256) void favor_reduce(
    const float* __restrict__ Sbkt,   // [32][4096]
    float* __restrict__ S)            // [4096]
{
    const int idx = blockIdx.x * 256 + threadIdx.x;   // [0,4096)
    float s = 0.f;
    #pragma unroll
    for (int j = 0; j < 32; ++j) s += Sbkt[j * 4096 + idx];
    S[idx] = s;
}

// ---------------- epilogue: y = [cos(pq),sin(pq)]/sqrt(8) @ S ----------------
__global__ __launch_bounds__(256) void favor_out(
    const float* __restrict__ pq,   // [NROWS][8]
    const float* __restrict__ S,    // [4][16][64]
    float* __restrict__ y)          // [NROWS][64]
{
    const int tid = threadIdx.x;
    const int blk = blockIdx.x;     // 0..511
    const int lane = tid & 63;
    const int w = __builtin_amdgcn_readfirstlane(tid >> 6);  // d-block 0..3
    const long row = (long)blk * 64 + lane;
    const int b = blk >> 7;         // 128 blocks per batch

    const float4 p0 = *(const float4*)(pq + row * 8);
    const float4 p1 = *(const float4*)(pq + row * 8 + 4);
    float qp[16];
    qp[0] = __cosf(p0.x) * INV_SQRT8;  qp[1] = __cosf(p0.y) * INV_SQRT8;
    qp[2] = __cosf(p0.z) * INV_SQRT8;  qp[3] = __cosf(p0.w) * INV_SQRT8;
    qp[4] = __cosf(p1.x) * INV_SQRT8;  qp[5] = __cosf(p1.y) * INV_SQRT8;
    qp[6] = __cosf(p1.z) * INV_SQRT8;  qp[7] = __cosf(p1.w) * INV_SQRT8;
    qp[8] = __sinf(p0.x) * INV_SQRT8;  qp[9] = __sinf(p0.y) * INV_SQRT8;
    qp[10]= __sinf(p0.z) * INV_SQRT8;  qp[11]= __sinf(p0.w) * INV_SQRT8;
    qp[12]= __sinf(p1.x) * INV_SQRT8;  qp[13]= __sinf(p1.y) * INV_SQRT8;
    qp[14]= __sinf(p1.z) * INV_SQRT8;  qp[15]= __sinf(p1.w) * INV_SQRT8;

    const float* Sb = S + b * 1024 + w * 16;   // wave-uniform -> scalar loads
    float a[16];
    #pragma unroll
    for (int i = 0; i < 16; ++i) a[i] = 0.f;
    #pragma unroll
    for (int m = 0; m < 16; ++m) {
        const float4 s0 = *(const float4*)(Sb + m * 64);
        const float4 s1 = *(const float4*)(Sb + m * 64 + 4);
        const float4 s2 = *(const float4*)(Sb + m * 64 + 8);
        const float4 s3 = *(const float4*)(Sb + m * 64 + 12);
        const float qm = qp[m];
        a[0] += qm * s0.x;  a[1] += qm * s0.y;  a[2] += qm * s0.z;  a[3] += qm * s0.w;
        a[4] += qm * s1.x;  a[5] += qm * s1.y;  a[6] += qm * s1.z;  a[7] += qm * s1.w;
        a[8] += qm * s2.x;  a[9] += qm * s2.y;  a[10]+= qm * s2.z;  a[11]+= qm * s2.w;
        a[12]+= qm * s3.x;  a[13]+= qm * s3.y;  a[14]+= qm * s3.z;  a[15]+= qm * s3.w;
    }
    float* yp = y + row * 64 + w * 16;
    *(float4*)(yp)      = make_float4(a[0],  a[1],  a[2],  a[3]);
    *(float4*)(yp + 4)  = make_float4(a[4],  a[5],  a[6],  a[7]);
    *(float4*)(yp + 8)  = make_float4(a[8],  a[9],  a[10], a[11]);
    *(float4*)(yp + 12) = make_float4(a[12], a[13], a[14], a[15]);
}

extern "C" void kernel_launch(void* const* d_in, const int* in_sizes, int n_in,
                              void* d_out, int out_size, void* d_ws, size_t ws_size,
                              hipStream_t stream) {
    const float* x  = (const float*)d_in[0];
    const float* w  = (const float*)d_in[1];
    const float* Wq = (const float*)d_in[2];
    const float* bq = (const float*)d_in[3];
    const float* Wk = (const float*)d_in[4];
    const float* bk = (const float*)d_in[5];
    const float* Wv = (const float*)d_in[6];
    const float* bv = (const float*)d_in[7];
    float* y = (float*)d_out;

    char* ws = (char*)d_ws;
    float*  S    = (float*)(ws);             // 16 KB   [4][16][64]
    float*  bqw  = (float*)(ws + 16384);
    float*  bkw  = (float*)(ws + 16448);
    __bf16* WpHS = (__bf16*)(ws + 32768);    // 32 KB   [32][64][8]
    __bf16* WpLS = (__bf16*)(ws + 65536);    // 32 KB
    __bf16* WvS  = (__bf16*)(ws + 98304);    // 128 KB  [4][32][64][8]
    float*  Sbkt = (float*)(ws + 229376);    // 512 KB  [32][4][16][64]
    float*  pq   = (float*)(ws + 786432);    // 1 MB    [32768][8]

    hipMemsetAsync(Sbkt, 0, 32 * 4096 * sizeof(float), stream);
    favor_setup<<<64, 256, 0, stream>>>(w, Wq, bq, Wk, bk, Wv, bqw, bkw, WpHS, WpLS, WvS);
    favor_main<<<1024, 256, 0, stream>>>(x, WvS, WpHS, WpLS, bqw, bkw, bv, pq, Sbkt);
    favor_reduce<<<16, 256, 0, stream>>>(Sbkt, S);
    favor_out<<<512, 256, 0, stream>>>(pq, S, y);
}

// Round 4
// 239.124 us; speedup vs baseline: 1.3513x; 1.1547x over previous
//
#include <hip/hip_runtime.h>
#include <cstdint>

#define E_DIM 1024
#define NROWS 32768
#define INV_SQRT8 0.35355339059327373f

typedef __bf16 bf16x8 __attribute__((ext_vector_type(8)));
typedef float f32x4 __attribute__((ext_vector_type(4)));
typedef const __attribute__((address_space(1))) void* gas_t;
typedef __attribute__((address_space(3))) void* las_t;

// ---------------- setup: fold W'=W@w, emit MFMA-fragment-swizzled bf16 tables ----------------
// WpHS/WpLS: [32 step][64 lane][8 j]  (hi/lo split of [Wq@w | Wk@w], B-frag order)
// WvS:       [4 ct][32 step][64 lane][8 j] of Wv (B-frag order)
__global__ __launch_bounds__(256) void favor_setup(
    const float* __restrict__ w,     // [64][8]
    const float* __restrict__ Wq,    // [1024][64]
    const float* __restrict__ bq,    // [64]
    const float* __restrict__ Wk,    // [1024][64]
    const float* __restrict__ bk,    // [64]
    const float* __restrict__ Wv,    // [1024][64]
    float* __restrict__ bqw,         // [8]
    float* __restrict__ bkw,         // [8]
    __bf16* __restrict__ WpHS,
    __bf16* __restrict__ WpLS,
    __bf16* __restrict__ WvS)
{
    const int g = blockIdx.x * 256 + threadIdx.x;  // 0..16383
    {
        const int k = g >> 4;
        const int c = g & 15;
        const float* Wsrc = (c < 8) ? Wq : Wk;
        const int cc = c & 7;
        float s = 0.f;
        #pragma unroll 8
        for (int d = 0; d < 64; ++d)
            s += Wsrc[k * 64 + d] * w[d * 8 + cc];
        const __bf16 h = (__bf16)s;
        const int step = k >> 5, quad = (k >> 3) & 3, j = k & 7;
        const int lane = quad * 16 + c;
        const int idx = (step * 64 + lane) * 8 + j;
        WpHS[idx] = h;
        WpLS[idx] = (__bf16)(s - (float)h);
    }
    #pragma unroll
    for (int t = 0; t < 4; ++t) {
        const int idx = g * 4 + t;        // [0, 65536)
        const int n = idx >> 10;          // 0..63
        const int k = idx & 1023;
        const int ct = n >> 4, l15 = n & 15;
        const int step = k >> 5, quad = (k >> 3) & 3, j = k & 7;
        const int lane = quad * 16 + l15;
        WvS[(((ct * 32 + step) * 64) + lane) * 8 + j] = (__bf16)Wv[k * 64 + n];
    }
    if (g < 16) {
        const int col = g & 7;
        const float* bb = (g < 8) ? bq : bk;
        float s1 = 0.f;
        #pragma unroll 8
        for (int d = 0; d < 64; ++d)
            s1 += bb[d] * w[d * 8 + col];
        if (g < 8) bqw[col] = s1; else bkw[col] = s1;
    }
}

// ---------------- main ----------------
// grid 1024 x 256. Block = 32 rows, K=1024 in 8 stages of 128 cols.
// Staging: global_load_lds width=16 into unpadded [32][128] tile, double-buffered.
// XOR swizzle: LDS[row][phys unit p (16B)] holds logical unit p^(row&31)
// (applied by permuting SOURCE lanes; dest is hardwired base+lane*16).
// Compute: wave wv = k-quarter (cols wv*32..+32 of each stage).
__global__ __launch_bounds__(256, 4) void favor_main(
    const float* __restrict__ x,      // [NROWS][1024]
    const __bf16* __restrict__ WvS,   // [4][32][64][8]
    const __bf16* __restrict__ WpHS,  // [32][64][8]
    const __bf16* __restrict__ WpLS,  // [32][64][8]
    const float* __restrict__ bqw,    // [8]
    const float* __restrict__ bkw,    // [8]
    const float* __restrict__ bv,     // [64]
    float* __restrict__ pq_out,       // [NROWS][8]
    float* __restrict__ Sbkt)         // [64][4][1024]
{
    __shared__ __align__(16) float smem[8448];   // 33792 B
    float* tile0 = smem;          // [32][128]
    float* tile1 = smem + 4096;
    // post-loop overlays (all uses separated by barriers):
    float* bufA = smem;           // [64][44]
    float* bufB = smem + 2816;
    float* bufC = smem + 5632;
    float* vb   = smem;           // [32][68]
    float* kp   = smem + 2176;    // [32][16]
    float* sred = smem + 2688;    // [3][64][20]

    const int tid  = threadIdx.x;
    const int wg   = blockIdx.x;                                // 0..1023
    const int lane = tid & 63;
    const int wv   = __builtin_amdgcn_readfirstlane(tid >> 6);  // 0..3
    const int l15  = lane & 15;
    const int quad = lane >> 4;

    // ---- staging source pointers: wave wv loads rows 8wv..8wv+7 (2 rows / instr) ----
    const int lrow_hi = lane >> 5;   // 0/1
    const float *src0, *src1, *src2, *src3;
    {
        const long rowbase = (long)wg * 32;
        const int r0 = wv * 8 + 0 + lrow_hi;
        const int r1 = wv * 8 + 2 + lrow_hi;
        const int r2 = wv * 8 + 4 + lrow_hi;
        const int r3 = wv * 8 + 6 + lrow_hi;
        src0 = x + (rowbase + r0) * E_DIM + (((lane & 31) ^ r0) * 4);
        src1 = x + (rowbase + r1) * E_DIM + (((lane & 31) ^ r1) * 4);
        src2 = x + (rowbase + r2) * E_DIM + (((lane & 31) ^ r2) * 4);
        src3 = x + (rowbase + r3) * E_DIM + (((lane & 31) ^ r3) * 4);
    }
    const int lo0 = (wv * 8 + 0) * 128;   // wave-uniform LDS float offsets
    const int lo1 = (wv * 8 + 2) * 128;
    const int lo2 = (wv * 8 + 4) * 128;
    const int lo3 = (wv * 8 + 6) * 128;

#define PF(tb, s)                                                                                        \
    __builtin_amdgcn_global_load_lds((gas_t)(src0 + (s) * 128), (las_t)((tb) + lo0), 16, 0, 0);          \
    __builtin_amdgcn_global_load_lds((gas_t)(src1 + (s) * 128), (las_t)((tb) + lo1), 16, 0, 0);          \
    __builtin_amdgcn_global_load_lds((gas_t)(src2 + (s) * 128), (las_t)((tb) + lo2), 16, 0, 0);          \
    __builtin_amdgcn_global_load_lds((gas_t)(src3 + (s) * 128), (las_t)((tb) + lo3), 16, 0, 0);

    // ---- fragment LDS byte offsets (XOR-swizzled, conflict-free) ----
    const int u0 = wv * 8 + quad * 2;
    const int fr0 = l15, fr1 = l15 + 16;
    const int fa00 = (fr0 * 128 + ((u0 ^ fr0) * 4)) * 4;
    const int fa01 = (fr0 * 128 + (((u0 + 1) ^ fr0) * 4)) * 4;
    const int fa10 = (fr1 * 128 + ((u0 ^ fr1) * 4)) * 4;
    const int fa11 = (fr1 * 128 + (((u0 + 1) ^ fr1) * 4)) * 4;

    f32x4 zero = {0.f, 0.f, 0.f, 0.f};
    f32x4 accv[4][2];
    #pragma unroll
    for (int ct = 0; ct < 4; ++ct) { accv[ct][0] = zero; accv[ct][1] = zero; }
    f32x4 accp[2] = {zero, zero};

    PF(tile0, 0)
    __syncthreads();

    #pragma unroll
    for (int s = 0; s < 8; ++s) {
        float* wb = (s & 1) ? tile1 : tile0;
        if (s < 7) {
            float* nb = (s & 1) ? tile0 : tile1;
            PF(nb, s + 1)
        }
        bf16x8 ah0, al0, ah1, al1;
        {
            const float4 a0 = *(const float4*)((const char*)wb + fa00);
            const float4 a1 = *(const float4*)((const char*)wb + fa01);
            const float f[8] = {a0.x, a0.y, a0.z, a0.w, a1.x, a1.y, a1.z, a1.w};
            #pragma unroll
            for (int i = 0; i < 8; ++i) {
                const __bf16 h = (__bf16)f[i];
                ah0[i] = h; al0[i] = (__bf16)(f[i] - (float)h);
            }
        }
        {
            const float4 a0 = *(const float4*)((const char*)wb + fa10);
            const float4 a1 = *(const float4*)((const char*)wb + fa11);
            const float f[8] = {a0.x, a0.y, a0.z, a0.w, a1.x, a1.y, a1.z, a1.w};
            #pragma unroll
            for (int i = 0; i < 8; ++i) {
                const __bf16 h = (__bf16)f[i];
                ah1[i] = h; al1[i] = (__bf16)(f[i] - (float)h);
            }
        }
        const int gs = s * 4 + wv;
        const __bf16* bp = WvS + (long)gs * 512 + lane * 8;
        #pragma unroll
        for (int ct = 0; ct < 4; ++ct) {
            const bf16x8 b = *(const bf16x8*)(bp + ct * 16384);
            accv[ct][0] = __builtin_amdgcn_mfma_f32_16x16x32_bf16(ah0, b, accv[ct][0], 0, 0, 0);
            accv[ct][1] = __builtin_amdgcn_mfma_f32_16x16x32_bf16(ah1, b, accv[ct][1], 0, 0, 0);
        }
        {
            const bf16x8 bh = *(const bf16x8*)(WpHS + (long)gs * 512 + lane * 8);
            const bf16x8 bl = *(const bf16x8*)(WpLS + (long)gs * 512 + lane * 8);
            accp[0] = __builtin_amdgcn_mfma_f32_16x16x32_bf16(ah0, bh, accp[0], 0, 0, 0);
            accp[0] = __builtin_amdgcn_mfma_f32_16x16x32_bf16(al0, bh, accp[0], 0, 0, 0);
            accp[0] = __builtin_amdgcn_mfma_f32_16x16x32_bf16(ah0, bl, accp[0], 0, 0, 0);
            accp[1] = __builtin_amdgcn_mfma_f32_16x16x32_bf16(ah1, bh, accp[1], 0, 0, 0);
            accp[1] = __builtin_amdgcn_mfma_f32_16x16x32_bf16(al1, bh, accp[1], 0, 0, 0);
            accp[1] = __builtin_amdgcn_mfma_f32_16x16x32_bf16(ah1, bl, accp[1], 0, 0, 0);
        }
        __syncthreads();
    }
#undef PF

    // ---- combine k-quarters: tree through LDS ----
    if (wv == 1 || wv == 3) {
        float* dst = ((wv == 1) ? bufA : bufB) + lane * 44;
        #pragma unroll
        for (int ct = 0; ct < 4; ++ct) {
            *(f32x4*)(dst + (ct * 2 + 0) * 4) = accv[ct][0];
            *(f32x4*)(dst + (ct * 2 + 1) * 4) = accv[ct][1];
        }
        *(f32x4*)(dst + 32) = accp[0];
        *(f32x4*)(dst + 36) = accp[1];
    }
    __syncthreads();
    if (wv == 0 || wv == 2) {
        const float* src = ((wv == 0) ? bufA : bufB) + lane * 44;
        #pragma unroll
        for (int ct = 0; ct < 4; ++ct) {
            accv[ct][0] += *(const f32x4*)(src + (ct * 2 + 0) * 4);
            accv[ct][1] += *(const f32x4*)(src + (ct * 2 + 1) * 4);
        }
        accp[0] += *(const f32x4*)(src + 32);
        accp[1] += *(const f32x4*)(src + 36);
    }
    if (wv == 2) {
        float* dst = bufC + lane * 44;
        #pragma unroll
        for (int ct = 0; ct < 4; ++ct) {
            *(f32x4*)(dst + (ct * 2 + 0) * 4) = accv[ct][0];
            *(f32x4*)(dst + (ct * 2 + 1) * 4) = accv[ct][1];
        }
        *(f32x4*)(dst + 32) = accp[0];
        *(f32x4*)(dst + 36) = accp[1];
    }
    __syncthreads();
    if (wv == 0) {
        const float* src = bufC + lane * 44;
        #pragma unroll
        for (int ct = 0; ct < 4; ++ct) {
            accv[ct][0] += *(const f32x4*)(src + (ct * 2 + 0) * 4);
            accv[ct][1] += *(const f32x4*)(src + (ct * 2 + 1) * 4);
        }
        accp[0] += *(const f32x4*)(src + 32);
        accp[1] += *(const f32x4*)(src + 36);

        // ---- p epilogue: accp[rh][r] = P[row = rh*16 + quad*4 + r][c = l15] ----
        if (l15 < 8) {
            const float bq_ = bqw[l15];
            #pragma unroll
            for (int rh = 0; rh < 2; ++rh)
                #pragma unroll
                for (int r = 0; r < 4; ++r) {
                    const long gr = (long)wg * 32 + rh * 16 + quad * 4 + r;
                    pq_out[gr * 8 + l15] = accp[rh][r] + bq_;
                }
        } else {
            const float bk_ = bkw[l15 - 8];
            #pragma unroll
            for (int rh = 0; rh < 2; ++rh)
                #pragma unroll
                for (int r = 0; r < 4; ++r) {
                    const int lr = rh * 16 + quad * 4 + r;
                    const float pk_ = accp[rh][r] + bk_;
                    kp[lr * 16 + (l15 - 8)] = __cosf(pk_) * INV_SQRT8;
                    kp[lr * 16 + l15]       = __sinf(pk_) * INV_SQRT8;
                }
        }
        // ---- v epilogue ----
        #pragma unroll
        for (int ct = 0; ct < 4; ++ct) {
            const float bv_ = bv[ct * 16 + l15];
            #pragma unroll
            for (int rh = 0; rh < 2; ++rh)
                #pragma unroll
                for (int r = 0; r < 4; ++r)
                    vb[(rh * 16 + quad * 4 + r) * 68 + ct * 16 + l15] = accv[ct][rh][r] + bv_;
        }
    }
    __syncthreads();

    // ---- S partial: S[m][d] += sum_r kp[r][m]*vb[r][d] over 32 rows ----
    {
        const int d4 = l15;          // d block of 4
        const int mg = quad;         // m block of 4
        const int rq = wv;           // row quarter (8 rows)
        float sa[16];
        #pragma unroll
        for (int i = 0; i < 16; ++i) sa[i] = 0.f;
        #pragma unroll
        for (int rr = 0; rr < 8; ++rr) {
            const int r = rq * 8 + rr;
            const float4 vv  = *(const float4*)(vb + r * 68 + d4 * 4);
            const float4 kk4 = *(const float4*)(kp + r * 16 + mg * 4);
            const float km[4] = {kk4.x, kk4.y, kk4.z, kk4.w};
            const float vm[4] = {vv.x, vv.y, vv.z, vv.w};
            #pragma unroll
            for (int mi = 0; mi < 4; ++mi)
                #pragma unroll
                for (int di = 0; di < 4; ++di)
                    sa[mi * 4 + di] += km[mi] * vm[di];
        }
        if (rq > 0) {
            float* dst = sred + (rq - 1) * 1280 + lane * 20;
            #pragma unroll
            for (int i = 0; i < 4; ++i)
                *(float4*)(dst + i * 4) = make_float4(sa[i*4], sa[i*4+1], sa[i*4+2], sa[i*4+3]);
        }
        __syncthreads();
        if (rq == 0) {
            #pragma unroll
            for (int j = 0; j < 3; ++j) {
                const float* src = sred + j * 1280 + lane * 20;
                #pragma unroll
                for (int i = 0; i < 16; ++i) sa[i] += src[i];
            }
            // bucket = wg & 63, batch = wg >> 8 -> 4 writers per address
            float* Sb = Sbkt + ((long)(wg & 63) * 4 + (wg >> 8)) * 1024;
            #pragma unroll
            for (int mi = 0; mi < 4; ++mi)
                #pragma unroll
                for (int di = 0; di < 4; ++di)
                    atomicAdd(&Sb[(mg * 4 + mi) * 64 + d4 * 4 + di], sa[mi * 4 + di]);
        }
    }
}

// ---------------- reduce buckets -> S ----------------
__global__ __launch_bounds__(256) void favor_reduce(
    const float* __restrict__ Sbkt,   // [64][4][1024]
    float* __restrict__ S)            // [4][1024]
{
    const int b   = blockIdx.x >> 2;               // batch 0..3
    const int col = (blockIdx.x & 3) * 256 + threadIdx.x;   // 0..1023
    float s = 0.f;
    #pragma unroll 8
    for (int j = 0; j < 64; ++j)
        s += Sbkt[((long)j * 4 + b) * 1024 + col];
    S[b * 1024 + col] = s;
}

// ---------------- epilogue: y = [cos(pq),sin(pq)]/sqrt(8) @ S ----------------
__global__ __launch_bounds__(256) void favor_out(
    const float* __restrict__ pq,   // [NROWS][8]
    const float* __restrict__ S,    // [4][16][64]
    float* __restrict__ y)          // [NROWS][64]
{
    const int tid = threadIdx.x;
    const int blk = blockIdx.x;     // 0..511
    const int lane = tid & 63;
    const int w = __builtin_amdgcn_readfirstlane(tid >> 6);  // d-block 0..3
    const long row = (long)blk * 64 + lane;
    const int b = blk >> 7;         // 128 blocks per batch

    const float4 p0 = *(const float4*)(pq + row * 8);
    const float4 p1 = *(const float4*)(pq + row * 8 + 4);
    float qp[16];
    qp[0] = __cosf(p0.x) * INV_SQRT8;  qp[1] = __cosf(p0.y) * INV_SQRT8;
    qp[2] = __cosf(p0.z) * INV_SQRT8;  qp[3] = __cosf(p0.w) * INV_SQRT8;
    qp[4] = __cosf(p1.x) * INV_SQRT8;  qp[5] = __cosf(p1.y) * INV_SQRT8;
    qp[6] = __cosf(p1.z) * INV_SQRT8;  qp[7] = __cosf(p1.w) * INV_SQRT8;
    qp[8] = __sinf(p0.x) * INV_SQRT8;  qp[9] = __sinf(p0.y) * INV_SQRT8;
    qp[10]= __sinf(p0.z) * INV_SQRT8;  qp[11]= __sinf(p0.w) * INV_SQRT8;
    qp[12]= __sinf(p1.x) * INV_SQRT8;  qp[13]= __sinf(p1.y) * INV_SQRT8;
    qp[14]= __sinf(p1.z) * INV_SQRT8;  qp[15]= __sinf(p1.w) * INV_SQRT8;

    const float* Sb = S + b * 1024 + w * 16;   // wave-uniform -> scalar loads
    float a[16];
    #pragma unroll
    for (int i = 0; i < 16; ++i) a[i] = 0.f;
    #pragma unroll
    for (int m = 0; m < 16; ++m) {
        const float4 s0 = *(const float4*)(Sb + m * 64);
        const float4 s1 = *(const float4*)(Sb + m * 64 + 4);
        const float4 s2 = *(const float4*)(Sb + m * 64 + 8);
        const float4 s3 = *(const float4*)(Sb + m * 64 + 12);
        const float qm = qp[m];
        a[0] += qm * s0.x;  a[1] += qm * s0.y;  a[2] += qm * s0.z;  a[3] += qm * s0.w;
        a[4] += qm * s1.x;  a[5] += qm * s1.y;  a[6] += qm * s1.z;  a[7] += qm * s1.w;
        a[8] += qm * s2.x;  a[9] += qm * s2.y;  a[10]+= qm * s2.z;  a[11]+= qm * s2.w;
        a[12]+= qm * s3.x;  a[13]+= qm * s3.y;  a[14]+= qm * s3.z;  a[15]+= qm * s3.w;
    }
    float* yp = y + row * 64 + w * 16;
    *(float4*)(yp)      = make_float4(a[0],  a[1],  a[2],  a[3]);
    *(float4*)(yp + 4)  = make_float4(a[4],  a[5],  a[6],  a[7]);
    *(float4*)(yp + 8)  = make_float4(a[8],  a[9],  a[10], a[11]);
    *(float4*)(yp + 12) = make_float4(a[12], a[13], a[14], a[15]);
}

extern "C" void kernel_launch(void* const* d_in, const int* in_sizes, int n_in,
                              void* d_out, int out_size, void* d_ws, size_t ws_size,
                              hipStream_t stream) {
    const float* x  = (const float*)d_in[0];
    const float* w  = (const float*)d_in[1];
    const float* Wq = (const float*)d_in[2];
    const float* bq = (const float*)d_in[3];
    const float* Wk = (const float*)d_in[4];
    const float* bk = (const float*)d_in[5];
    const float* Wv = (const float*)d_in[6];
    const float* bv = (const float*)d_in[7];
    float* y = (float*)d_out;

    char* ws = (char*)d_ws;
    float*  S    = (float*)(ws);             // 16 KB   [4][1024]
    float*  bqw  = (float*)(ws + 16384);
    float*  bkw  = (float*)(ws + 16448);
    __bf16* WpHS = (__bf16*)(ws + 32768);    // 32 KB   [32][64][8]
    __bf16* WpLS = (__bf16*)(ws + 65536);    // 32 KB
    __bf16* WvS  = (__bf16*)(ws + 98304);    // 128 KB  [4][32][64][8]
    float*  Sbkt = (float*)(ws + 229376);    // 1 MB    [64][4][1024]
    float*  pq   = (float*)(ws + 1277952);   // 1 MB    [32768][8]

    hipMemsetAsync(Sbkt, 0, 64 * 4 * 1024 * sizeof(float), stream);
    favor_setup<<<64, 256, 0, stream>>>(w, Wq, bq, Wk, bk, Wv, bqw, bkw, WpHS, WpLS, WvS);
    favor_main<<<1024, 256, 0, stream>>>(x, WvS, WpHS, WpLS, bqw, bkw, bv, pq, Sbkt);
    favor_reduce<<<16, 256, 0, stream>>>(Sbkt, S);
    favor_out<<<512, 256, 0, stream>>>(pq, S, y);
}